// Round 2
// baseline (9195.025 us; speedup 1.0000x reference)
//
#include <hip/hip_runtime.h>
#include <hip/hip_bf16.h>
#include <stdint.h>

#define VOCAB 32000
#define HIDDEN 512
#define TSEQ 1024
#define NWG 8

typedef __attribute__((ext_vector_type(4))) float f32x4;
typedef __attribute__((ext_vector_type(8))) short short8;

// ---------------- kernel: f32 -> bf16 convert (Why_w) ----------------
__global__ __launch_bounds__(256) void k_convert(const float* __restrict__ in,
                                                 __hip_bfloat16* __restrict__ out,
                                                 int n4) {
  int stride = gridDim.x * blockDim.x;
  for (int i = blockIdx.x * blockDim.x + threadIdx.x; i < n4; i += stride) {
    const float4 v = *reinterpret_cast<const float4*>(in + (size_t)i * 4);
    union { __hip_bfloat16 h[4]; ushort4 u; } p;
    p.h[0] = __float2bfloat16(v.x);
    p.h[1] = __float2bfloat16(v.y);
    p.h[2] = __float2bfloat16(v.z);
    p.h[3] = __float2bfloat16(v.w);
    *reinterpret_cast<ushort4*>(out + (size_t)i * 4) = p.u;
  }
}

// ---------------- kernel: pre[t][j] = Wxh_w[j][idx[t]] + Wxh_b[j] + Whh_b[j] ----------------
__global__ __launch_bounds__(512) void k_pre(const int* __restrict__ idx,
                                             const float* __restrict__ h0,
                                             const float* __restrict__ Wxh_w,
                                             const float* __restrict__ Wxh_b,
                                             const float* __restrict__ Whh_b,
                                             float* __restrict__ pre,
                                             float* __restrict__ h_hist) {
  const int t = blockIdx.x;
  const int j = threadIdx.x;
  const int c = idx[t];
  pre[(size_t)t * HIDDEN + j] = Wxh_w[(size_t)j * VOCAB + c] + Wxh_b[j] + Whh_b[j];
  if (t == 0) h_hist[j] = h0[j];  // h_hist[0] = initial hidden state
}

// ---------------- kernel: the sequential scan ----------------
// 8 WGs x 512 threads. WG g owns rows [64g, 64g+64). Thread (r=tid>>3, s=tid&7)
// holds Whh[64g+r][64s..64s+64) in 16 f32x4 PINNED in VGPRs (asm keep-alive).
// Cross-WG handshake entirely via sc0+sc1 (memory-side coherent point) accesses:
//   producer: sc1-store 64 h values, s_waitcnt vmcnt(0), per-wave relaxed
//             agent fetch_add on flags[t*8+g] (counter -> 8 when WG done)
//   consumer: thread needs exactly producer WG s's slice -> polls flags[(t-1)*8+s]
//             with relaxed agent loads (sc1, no buffer_inv), then sc1-loads the
//             64-float chunk in one 16x dwordx4 asm block ending in vmcnt(0).
// No __syncthreads in the loop; no whole-L2 wbl2/inv anywhere.
__global__ __launch_bounds__(512, 2) void k_scan(const float* __restrict__ pre,
                                                 const float* __restrict__ Whh,
                                                 float* __restrict__ h_hist,
                                                 __hip_bfloat16* __restrict__ h_bf,
                                                 unsigned* __restrict__ flags,
                                                 float* __restrict__ h_final) {
  const int g = blockIdx.x;
  const int tid = threadIdx.x;
  const int r = tid >> 3;      // 0..63
  const int s = tid & 7;       // 0..7  (chunk index == producer WG index)
  const int R = g * 64 + r;    // global row this thread helps compute

  f32x4 w[16];
  const f32x4* wp = reinterpret_cast<const f32x4*>(Whh + (size_t)R * HIDDEN + s * 64);
#pragma unroll
  for (int i = 0; i < 16; ++i) w[i] = wp[i];
#pragma unroll
  for (int i = 0; i < 16; ++i) asm volatile("" : "+v"(w[i]));  // pin in VGPRs

  for (int t = 1; t <= TSEQ; ++t) {
    const float pv = pre[(size_t)(t - 1) * HIDDEN + R];

    if (t > 1) {
      const unsigned* fp = &flags[(size_t)(t - 1) * NWG + s];
      while (__hip_atomic_load(fp, __ATOMIC_RELAXED, __HIP_MEMORY_SCOPE_AGENT) < 8u) {}
    }

    const float* hbase = h_hist + (size_t)(t - 1) * HIDDEN + s * 64;
    f32x4 hv[16];
    asm volatile(
        "global_load_dwordx4 %0, %16, off sc0 sc1\n\t"
        "global_load_dwordx4 %1, %16, off offset:16 sc0 sc1\n\t"
        "global_load_dwordx4 %2, %16, off offset:32 sc0 sc1\n\t"
        "global_load_dwordx4 %3, %16, off offset:48 sc0 sc1\n\t"
        "global_load_dwordx4 %4, %16, off offset:64 sc0 sc1\n\t"
        "global_load_dwordx4 %5, %16, off offset:80 sc0 sc1\n\t"
        "global_load_dwordx4 %6, %16, off offset:96 sc0 sc1\n\t"
        "global_load_dwordx4 %7, %16, off offset:112 sc0 sc1\n\t"
        "global_load_dwordx4 %8, %16, off offset:128 sc0 sc1\n\t"
        "global_load_dwordx4 %9, %16, off offset:144 sc0 sc1\n\t"
        "global_load_dwordx4 %10, %16, off offset:160 sc0 sc1\n\t"
        "global_load_dwordx4 %11, %16, off offset:176 sc0 sc1\n\t"
        "global_load_dwordx4 %12, %16, off offset:192 sc0 sc1\n\t"
        "global_load_dwordx4 %13, %16, off offset:208 sc0 sc1\n\t"
        "global_load_dwordx4 %14, %16, off offset:224 sc0 sc1\n\t"
        "global_load_dwordx4 %15, %16, off offset:240 sc0 sc1\n\t"
        "s_waitcnt vmcnt(0)"
        : "=&v"(hv[0]), "=&v"(hv[1]), "=&v"(hv[2]), "=&v"(hv[3]),
          "=&v"(hv[4]), "=&v"(hv[5]), "=&v"(hv[6]), "=&v"(hv[7]),
          "=&v"(hv[8]), "=&v"(hv[9]), "=&v"(hv[10]), "=&v"(hv[11]),
          "=&v"(hv[12]), "=&v"(hv[13]), "=&v"(hv[14]), "=&v"(hv[15])
        : "v"(hbase)
        : "memory");

    float acc = 0.f;
#pragma unroll
    for (int i = 0; i < 16; ++i) {
      acc += w[i][0] * hv[i][0];
      acc += w[i][1] * hv[i][1];
      acc += w[i][2] * hv[i][2];
      acc += w[i][3] * hv[i][3];
    }
    // reduce across the 8 chunk-lanes of this row (lanes 8k..8k+7)
    acc += __shfl_xor(acc, 1);
    acc += __shfl_xor(acc, 2);
    acc += __shfl_xor(acc, 4);

    float y = 0.f;
    if (s == 0) {
      y = tanhf(pv + acc);
      const float* ha = h_hist + (size_t)t * HIDDEN + R;
      asm volatile("global_store_dword %0, %1, off sc0 sc1"
                   :: "v"(ha), "v"(y) : "memory");
    }
    asm volatile("s_waitcnt vmcnt(0)" ::: "memory");  // wave's h stores acked at coherent point
    if ((tid & 63) == 0) {
      __hip_atomic_fetch_add(&flags[(size_t)t * NWG + g], 1u,
                             __ATOMIC_RELAXED, __HIP_MEMORY_SCOPE_AGENT);
    }
    // off the critical path: bf16 history + final h
    if (s == 0) {
      h_bf[(size_t)(t - 1) * HIDDEN + R] = __float2bfloat16(y);
      if (t == TSEQ) h_final[R] = y;
    }
  }
}

// ---------------- kernel: logits = h_seq @ Why_w^T + bias (bf16 MFMA) ----------------
// A: [TSEQ][HIDDEN] bf16 (h_seq), B: [VOCAB][HIDDEN] bf16 (Why_w), both K-contiguous.
// 128x128 tile, 4 waves in 2x2 of 64x64, 16x16x32 bf16 MFMA, BK=32.
__global__ __launch_bounds__(256) void k_gemm(const __hip_bfloat16* __restrict__ A,
                                              const __hip_bfloat16* __restrict__ B,
                                              const float* __restrict__ bias,
                                              float* __restrict__ C) {
  __shared__ __hip_bfloat16 As[128][32];
  __shared__ __hip_bfloat16 Bs[128][32];
  const int bn = blockIdx.x;  // 0..249
  const int bm = blockIdx.y;  // 0..7
  const int tid = threadIdx.x;
  const int lane = tid & 63;
  const int wid = tid >> 6;
  const int wr = (wid >> 1) * 64;
  const int wc = (wid & 1) * 64;
  const int l15 = lane & 15;
  const int kc = lane >> 4;

  const int sr = tid >> 1;        // staging row 0..127
  const int sc = (tid & 1) * 16;  // staging k offset {0,16}

  const __hip_bfloat16* Ag = A + (size_t)(bm * 128 + sr) * HIDDEN + sc;
  const __hip_bfloat16* Bg = B + (size_t)(bn * 128 + sr) * HIDDEN + sc;

  f32x4 acc[4][4];
#pragma unroll
  for (int m = 0; m < 4; ++m)
#pragma unroll
    for (int n = 0; n < 4; ++n) {
      acc[m][n][0] = 0.f; acc[m][n][1] = 0.f; acc[m][n][2] = 0.f; acc[m][n][3] = 0.f;
    }

  for (int ks = 0; ks < HIDDEN; ks += 32) {
    __syncthreads();  // WAR: previous iteration's reads done
    *reinterpret_cast<short8*>(&As[sr][sc])     = *reinterpret_cast<const short8*>(Ag + ks);
    *reinterpret_cast<short8*>(&As[sr][sc + 8]) = *reinterpret_cast<const short8*>(Ag + ks + 8);
    *reinterpret_cast<short8*>(&Bs[sr][sc])     = *reinterpret_cast<const short8*>(Bg + ks);
    *reinterpret_cast<short8*>(&Bs[sr][sc + 8]) = *reinterpret_cast<const short8*>(Bg + ks + 8);
    __syncthreads();

    short8 af[4], bfr[4];
#pragma unroll
    for (int m = 0; m < 4; ++m)
      af[m] = *reinterpret_cast<const short8*>(&As[wr + m * 16 + l15][kc * 8]);
#pragma unroll
    for (int n = 0; n < 4; ++n)
      bfr[n] = *reinterpret_cast<const short8*>(&Bs[wc + n * 16 + l15][kc * 8]);
#pragma unroll
    for (int m = 0; m < 4; ++m)
#pragma unroll
      for (int n = 0; n < 4; ++n)
        acc[m][n] = __builtin_amdgcn_mfma_f32_16x16x32_bf16(af[m], bfr[n], acc[m][n], 0, 0, 0);
  }

  // epilogue: C/D layout col = lane&15, row = (lane>>4)*4 + q
#pragma unroll
  for (int m = 0; m < 4; ++m) {
#pragma unroll
    for (int n = 0; n < 4; ++n) {
      const int vcol = bn * 128 + wc + n * 16 + l15;
      const float bv = bias[vcol];
#pragma unroll
      for (int q = 0; q < 4; ++q) {
        const int trow = bm * 128 + wr + m * 16 + kc * 4 + q;
        C[(size_t)trow * VOCAB + vcol] = acc[m][n][q] + bv;
      }
    }
  }
}

extern "C" void kernel_launch(void* const* d_in, const int* in_sizes, int n_in,
                              void* d_out, int out_size, void* d_ws, size_t ws_size,
                              hipStream_t stream) {
  (void)in_sizes; (void)n_in; (void)out_size; (void)ws_size;

  const int*   idx   = (const int*)d_in[0];
  const float* h0    = (const float*)d_in[1];
  const float* Wxh_w = (const float*)d_in[2];
  const float* Wxh_b = (const float*)d_in[3];
  const float* Whh_w = (const float*)d_in[4];
  const float* Whh_b = (const float*)d_in[5];
  const float* Why_w = (const float*)d_in[6];
  const float* Why_b = (const float*)d_in[7];
  float* out = (float*)d_out;

  // workspace layout (bytes)
  char* ws = (char*)d_ws;
  __hip_bfloat16* why_bf = (__hip_bfloat16*)(ws);                       // 32,768,000
  float* pre    = (float*)(ws + 32768000);                              // 2,097,152
  float* h_hist = (float*)(ws + 32768000 + 2097152);                    // 2,099,200 (1025 rows)
  __hip_bfloat16* h_bf = (__hip_bfloat16*)(ws + 32768000 + 2097152 + 2099200); // 1,048,576
  unsigned* flags = (unsigned*)(ws + 32768000 + 2097152 + 2099200 + 1048576);  // 32,800

  // flags must be zeroed every call (ws is not re-poisoned between replays)
  hipMemsetAsync(flags, 0, (size_t)(TSEQ + 1) * NWG * sizeof(unsigned), stream);

  k_convert<<<2048, 256, 0, stream>>>(Why_w, why_bf, (VOCAB * HIDDEN) / 4);
  k_pre<<<TSEQ, HIDDEN, 0, stream>>>(idx, h0, Wxh_w, Wxh_b, Whh_b, pre, h_hist);
  k_scan<<<NWG, 512, 0, stream>>>(pre, Whh_w, h_hist, h_bf, flags, out + 32768000);
  k_gemm<<<dim3(VOCAB / 128, TSEQ / 128), 256, 0, stream>>>(h_bf, why_bf, Why_b, out);
}